// Round 7
// baseline (311.192 us; speedup 1.0000x reference)
//
#include <hip/hip_runtime.h>
#include <hip/hip_bf16.h>

// SpikingSelfAttention: T=4 B=32 C=384 N=256 NH=8 D=48
#define T_  4
#define B_  32
#define C_  384
#define N_  256
#define NH_ 8
#define D_  48

typedef __attribute__((ext_vector_type(8))) short bf16x8;
typedef __attribute__((ext_vector_type(4))) float f32x4;

__device__ __forceinline__ float bf2f(unsigned short s) {
    return __uint_as_float(((unsigned int)s) << 16);
}
__device__ __forceinline__ unsigned short f2bf(float f) {
    __hip_bfloat16 h = __float2bfloat16(f);
    return __builtin_bit_cast(unsigned short, h);
}

// ---- K0: split fp32 weights into hi/lo bf16, FRAGMENT-MAJOR [otile24][ks12][lane64][8] ----
__global__ __launch_bounds__(256) void k_wsplit(const float* __restrict__ w0,
                                                const float* __restrict__ w1,
                                                const float* __restrict__ w2,
                                                const float* __restrict__ w3,
                                                unsigned short* __restrict__ hi,
                                                unsigned short* __restrict__ lo) {
    const float* w = (blockIdx.y==0) ? w0 : (blockIdx.y==1) ? w1 : (blockIdx.y==2) ? w2 : w3;
    int g = blockIdx.x*256 + threadIdx.x;            // 0..18431 (72 blocks)
    int otile = g / 768;
    int rem = g - otile*768;
    int lane = rem & 63;
    int o  = otile*16 + (lane & 15);
    int k0 = (rem >> 6)*32 + (lane >> 4)*8;
    const float* src = w + (size_t)o*C_ + k0;
    unsigned short h8[8], l8[8];
    #pragma unroll
    for (int j=0;j<8;++j) {
        float f = src[j];
        h8[j] = f2bf(f);
        l8[j] = f2bf(f - bf2f(h8[j]));
    }
    size_t dst = (size_t)blockIdx.y*147456 + (size_t)g*8;
    *(uint4*)(hi + dst) = *(uint4*)h8;
    *(uint4*)(lo + dst) = *(uint4*)l8;
}

// ---- K1: LIF over T on x; spikes bf16 FRAGMENT-MAJOR: [t][b][ntile16][ks12][lane64][8] ----
__global__ __launch_bounds__(256) void k_lif1(const float* __restrict__ x,
                                              unsigned short* __restrict__ s0) {
    __shared__ unsigned short Tt[64*72];
    const int tid = threadIdx.x;
    const int b  = blockIdx.x;
    const int c0 = blockIdx.y * 64;
    const int n0 = blockIdx.z * 64;
    const int ci = tid >> 2;
    const int nj = (tid & 3) * 16;
    float v[16];
    #pragma unroll
    for (int i=0;i<16;++i) v[i]=0.f;
    for (int t = 0; t < T_; ++t) {
        const float* xp = x + (((size_t)t*B_ + b)*C_ + c0 + ci)*N_ + n0 + nj;
        #pragma unroll
        for (int q=0;q<4;++q) {
            float4 f = *(const float4*)(xp + q*4);
            float e[4] = {f.x,f.y,f.z,f.w};
            #pragma unroll
            for (int j=0;j<4;++j) {
                int ii = q*4+j;
                float h = v[ii] + (e[j] - v[ii])*0.5f;
                bool sp = (h - 1.0f) >= 0.f;
                v[ii] = sp ? 0.f : h;
                Tt[(nj + ii)*72 + ci] = sp ? 0x3F80u : 0u;
            }
        }
        __syncthreads();
        int nrow = tid >> 2, cch = (tid & 3)*16;
        int n = n0 + nrow;
        uint4 u0 = *(const uint4*)&Tt[nrow*72 + cch];
        uint4 u1 = *(const uint4*)&Tt[nrow*72 + cch + 8];
        size_t tb16 = ((size_t)(t*B_ + b)*16 + (n>>4))*12;
        int c8a = c0 + cch, c8b = c0 + cch + 8;
        *(uint4*)(s0 + (tb16 + (c8a>>5))*512 + (((c8a>>3)&3)*16 + (n&15))*8) = u0;
        *(uint4*)(s0 + (tb16 + (c8b>>5))*512 + (((c8b>>3)&3)*16 + (n&15))*8) = u1;
        __syncthreads();
    }
}

// ---- K2: MFMA branch GEMM, 128x256 tiles; Q/K/V spikes out in [t][b][o][n] (dense stores) ----
struct Br2 {
    const unsigned short* whi[3];
    const unsigned short* wlo[3];
    const float *g[3], *be[3], *me[3], *va[3];
    unsigned short* out[3];
};

__global__ __launch_bounds__(256, 2) void k_branch(const unsigned short* __restrict__ s0, Br2 a) {
    __shared__ float Ep[32*260];
    __shared__ float BNi[128], BNo[128];
    const int tid = threadIdx.x;
    const int z  = blockIdx.z;
    const int o0 = blockIdx.y * 128;
    const int bx = blockIdx.x;               // col-tile fastest for L2 affinity
    const int b  = bx >> 2;
    const int n0 = (bx & 3) * 64;
    const int w    = tid >> 6;
    const int lane = tid & 63;
    const int quad = lane >> 4;
    const int lc   = lane & 15;
    const unsigned short* __restrict__ Wgh = a.whi[z];
    const unsigned short* __restrict__ Wgl = a.wlo[z];

    if (tid < 128) {
        int o = o0 + tid;
        float inv = a.g[z][o] / sqrtf(a.va[z][o] + 1e-5f);
        BNi[tid] = inv;
        BNo[tid] = a.be[z][o] - a.me[z][o]*inv;
    }

    const int base_ot = (o0 >> 4) + (w >> 1)*4;
    const unsigned short* pAh[4];
    const unsigned short* pAl[4];
    const unsigned short* pB[8];
    #pragma unroll
    for (int mt=0;mt<4;++mt) {
        size_t off = (size_t)(base_ot + mt)*6144 + lane*8;
        pAh[mt] = Wgh + off;
        pAl[mt] = Wgl + off;
    }
    #pragma unroll
    for (int nt=0;nt<8;++nt) {
        int cb = (w&1)*128 + nt*16;
        int t = cb >> 6;
        int ntile = (n0 >> 4) + ((cb & 63) >> 4);
        pB[nt] = s0 + ((size_t)(t*B_ + b)*16 + ntile)*6144 + lane*8;
    }

    f32x4 acc[4][8];
    #pragma unroll
    for (int mt=0;mt<4;++mt)
        #pragma unroll
        for (int nt=0;nt<8;++nt) { acc[mt][nt][0]=0.f; acc[mt][nt][1]=0.f; acc[mt][nt][2]=0.f; acc[mt][nt][3]=0.f; }

    #pragma unroll
    for (int ks = 0; ks < 12; ++ks) {
        bf16x8 ah[4], al[4], bb[8];
        #pragma unroll
        for (int mt=0;mt<4;++mt) {
            ah[mt] = *(const bf16x8*)(pAh[mt]); pAh[mt] += 512;
            al[mt] = *(const bf16x8*)(pAl[mt]); pAl[mt] += 512;
        }
        #pragma unroll
        for (int nt=0;nt<8;++nt) { bb[nt] = *(const bf16x8*)(pB[nt]); pB[nt] += 512; }
        #pragma unroll
        for (int mt=0;mt<4;++mt)
            #pragma unroll
            for (int nt=0;nt<8;++nt) {
                acc[mt][nt] = __builtin_amdgcn_mfma_f32_16x16x32_bf16(ah[mt], bb[nt], acc[mt][nt], 0,0,0);
                acc[mt][nt] = __builtin_amdgcn_mfma_f32_16x16x32_bf16(al[mt], bb[nt], acc[mt][nt], 0,0,0);
            }
    }

    // epilogue: 4 rounds; Ep = 32 o x 256 col (col = t*64 + nn); dense [t][b][o][n] stores
    unsigned short* out = a.out[z];
    for (int r = 0; r < 4; ++r) {
        __syncthreads();
        int erow = (w>>1)*16 + quad*4;
        #pragma unroll
        for (int nt=0;nt<8;++nt) {
            int col = (w&1)*128 + nt*16 + lc;
            Ep[(erow+0)*260 + col] = acc[r][nt][0];
            Ep[(erow+1)*260 + col] = acc[r][nt][1];
            Ep[(erow+2)*260 + col] = acc[r][nt][2];
            Ep[(erow+3)*260 + col] = acc[r][nt][3];
        }
        __syncthreads();
        {
            int orow = tid >> 3;                 // 0..31
            int ns8 = (tid & 7) * 8;
            int oloc = ((orow & 16) ? 64 : 0) + r*16 + (orow & 15);
            int o = o0 + oloc;
            float inv = BNi[oloc], off = BNo[oloc];
            float v[8];
            #pragma unroll
            for (int j=0;j<8;++j) v[j]=0.f;
            #pragma unroll
            for (int t=0;t<4;++t) {
                float4 f0 = *(const float4*)&Ep[orow*260 + t*64 + ns8];
                float4 f1 = *(const float4*)&Ep[orow*260 + t*64 + ns8 + 4];
                float e[8] = {f0.x,f0.y,f0.z,f0.w,f1.x,f1.y,f1.z,f1.w};
                unsigned short sp8[8];
                #pragma unroll
                for (int j=0;j<8;++j) {
                    float y = e[j]*inv + off;
                    float h = v[j] + (y - v[j])*0.5f;
                    bool sp = (h - 1.0f) >= 0.f;
                    v[j] = sp ? 0.f : h;
                    sp8[j] = sp ? 0x3F80u : 0u;
                }
                *(uint4*)(out + ((size_t)(t*B_ + b)*C_ + o)*N_ + n0 + ns8) = *(uint4*)sp8;
            }
        }
    }
}

// ---- K3: attention per (t,b,h) via MFMA: AO = Q (K^T V) * 0.125, fp32 [t][bh][n][48] ----
// Phase1: KtV[dd1][dd2] = sum_n K[dd1][n]*V[dd2][n]  (A,B frags direct from global, L1/L2-hot)
// Phase2: AO[n][dd2]    = sum_dd Qt[n][dd]*KtVb[dd2][dd]  (Qt, KtVb in LDS; KtVb bf16 exact ints <=256)
__global__ __launch_bounds__(256) void k_attn(const unsigned short* __restrict__ qs,
                                              const unsigned short* __restrict__ ks,
                                              const unsigned short* __restrict__ vs,
                                              float* __restrict__ ao) {
    __shared__ unsigned short Qt[256*72];        // [n][dd], dd padded to 72 (48..63 zeroed)
    __shared__ unsigned short KtVb[48*72];       // [dd2][dd], bf16, dd 48..63 zeroed
    const int tid = threadIdx.x;
    const int w = tid >> 6, lane = tid & 63, quad = lane >> 4, lc = lane & 15;
    const int t  = blockIdx.x >> 8;
    const int bh = blockIdx.x & 255;
    const int b  = bh >> 3, hh = bh & 7;
    const size_t gbase = ((size_t)(t*B_ + b)*C_ + hh*D_)*N_;   // 48x256 contiguous slab

    // phase 0: stage Q transposed into Qt (bank-staggered scalar writes) + zero pads
    #pragma unroll
    for (int i=0;i<6;++i) {
        int q = tid + i*256;
        int dd = q >> 5, n8 = (q & 31)*8;
        uint4 u = *(const uint4*)(qs + gbase + (size_t)dd*N_ + n8);
        unsigned short tmp[8]; *(uint4*)tmp = u;
        #pragma unroll
        for (int jj=0;jj<8;++jj) {
            int j = (jj + lane) & 7;
            Qt[(n8 + j)*72 + dd] = tmp[j];
        }
    }
    #pragma unroll
    for (int i=0;i<2;++i) {
        int q = tid + i*256;                     // 512 chunks: row = q>>1, half = q&1
        *(uint4*)&Qt[(q>>1)*72 + 48 + (q&1)*8] = make_uint4(0,0,0,0);
    }
    for (int i = tid; i < 432; i += 256)
        *(uint4*)&KtVb[i*8] = make_uint4(0,0,0,0);
    __syncthreads();

    // phase 1: waves 0..2 compute KtV strips (M=48 -> 3x16), N=48 (3 tiles), K=256 (8 steps)
    if (w < 3) {
        f32x4 acc[3];
        #pragma unroll
        for (int nt=0;nt<3;++nt) { acc[nt][0]=0.f; acc[nt][1]=0.f; acc[nt][2]=0.f; acc[nt][3]=0.f; }
        const unsigned short* kbase = ks + gbase + (size_t)(w*16 + lc)*N_ + quad*8;
        #pragma unroll
        for (int k2=0; k2<8; ++k2) {
            bf16x8 af = *(const bf16x8*)(kbase + k2*32);
            #pragma unroll
            for (int nt=0;nt<3;++nt) {
                bf16x8 bf = *(const bf16x8*)(vs + gbase + (size_t)(nt*16 + lc)*N_ + k2*32 + quad*8);
                acc[nt] = __builtin_amdgcn_mfma_f32_16x16x32_bf16(af, bf, acc[nt], 0,0,0);
            }
        }
        // store transposed: KtVb[dd2][dd1], exact small ints -> bf16 exact
        #pragma unroll
        for (int nt=0;nt<3;++nt)
            #pragma unroll
            for (int r=0;r<4;++r)
                KtVb[(nt*16 + lc)*72 + w*16 + quad*4 + r] = f2bf(acc[nt][r]);
    }
    __syncthreads();

    // phase 2: all 4 waves, M=256 (16 tiles /4 per wave), N=48, K=64 (2 steps)
    f32x4 acc2[4][3];
    #pragma unroll
    for (int j=0;j<4;++j)
        #pragma unroll
        for (int nt=0;nt<3;++nt) { acc2[j][nt][0]=0.f; acc2[j][nt][1]=0.f; acc2[j][nt][2]=0.f; acc2[j][nt][3]=0.f; }
    #pragma unroll
    for (int k2=0; k2<2; ++k2) {
        bf16x8 bfr[3];
        #pragma unroll
        for (int nt=0;nt<3;++nt)
            bfr[nt] = *(const bf16x8*)&KtVb[(nt*16 + lc)*72 + k2*32 + quad*8];
        #pragma unroll
        for (int j=0;j<4;++j) {
            int mt = w*4 + j;
            bf16x8 af = *(const bf16x8*)&Qt[(mt*16 + lc)*72 + k2*32 + quad*8];
            #pragma unroll
            for (int nt=0;nt<3;++nt)
                acc2[j][nt] = __builtin_amdgcn_mfma_f32_16x16x32_bf16(af, bfr[nt], acc2[j][nt], 0,0,0);
        }
    }
    float* aout = ao + (size_t)blockIdx.x * 12288;   // [n][48]
    #pragma unroll
    for (int j=0;j<4;++j) {
        int nr = (w*4 + j)*16 + quad*4;
        #pragma unroll
        for (int nt=0;nt<3;++nt)
            #pragma unroll
            for (int r=0;r<4;++r)
                aout[(size_t)(nr + r)*48 + nt*16 + lc] = acc2[j][nt][r]*0.125f;
    }
}

// ---- K4: attn LIF over T: AO [t][bh][n][48] -> S2 fragment-major; grid (bh, ddc) ----
__global__ __launch_bounds__(256) void k_lif3(const float* __restrict__ ao,
                                              unsigned short* __restrict__ s2) {
    const int tid = threadIdx.x;                 // n
    const int bh = blockIdx.x;                   // 0..255
    const int ddc = blockIdx.y;                  // 0..5
    const int b2 = bh >> 3, hh = bh & 7;
    const int ci = hh*6 + ddc;
    float v[8];
    #pragma unroll
    for (int j=0;j<8;++j) v[j]=0.f;
    for (int t=0;t<T_;++t) {
        const float* ap = ao + ((size_t)(t*256 + bh)*256 + tid)*48 + ddc*8;
        float4 f0 = *(const float4*)ap;
        float4 f1 = *(const float4*)(ap + 4);
        float e[8] = {f0.x,f0.y,f0.z,f0.w,f1.x,f1.y,f1.z,f1.w};
        unsigned short sp[8];
        #pragma unroll
        for (int j=0;j<8;++j) {
            float h = v[j] + (e[j] - v[j])*0.5f;
            bool s = (h - 1.0f) >= 0.f;
            v[j] = s ? 0.f : h;
            sp[j] = s ? 0x3F80u : 0u;
        }
        size_t tb16 = ((size_t)(t*B_ + b2)*16 + (tid>>4))*12;
        size_t dst = (tb16 + (ci>>2))*512 + (size_t)(((ci&3)*16 + (tid&15))*8);
        *(uint4*)(s2 + dst) = *(uint4*)sp;
    }
}

// ---- K5: proj MFMA GEMM + bias + BN -> out [T][B][C][N] fp32, 128x256 tiles ----
__global__ __launch_bounds__(256, 2) void k_proj(const unsigned short* __restrict__ s2,
        const unsigned short* __restrict__ Wgh, const unsigned short* __restrict__ Wgl,
        const float* __restrict__ pb,
        const float* __restrict__ g, const float* __restrict__ be,
        const float* __restrict__ me, const float* __restrict__ va,
        float* __restrict__ out) {
    __shared__ float Ep[32*260];
    __shared__ float BNi[128], BNo[128];
    const int tid = threadIdx.x;
    const int o0 = blockIdx.y * 128;
    const int bx = blockIdx.x;
    const int b  = bx >> 2;
    const int n0 = (bx & 3) * 64;
    const int w    = tid >> 6;
    const int lane = tid & 63;
    const int quad = lane >> 4;
    const int lc   = lane & 15;

    if (tid < 128) {
        int o = o0 + tid;
        float inv = g[o] / sqrtf(va[o] + 1e-5f);
        BNi[tid] = inv;
        BNo[tid] = be[o] - me[o]*inv + pb[o]*inv;
    }

    const int base_ot = (o0 >> 4) + (w >> 1)*4;
    const unsigned short* pAh[4];
    const unsigned short* pAl[4];
    const unsigned short* pB[8];
    #pragma unroll
    for (int mt=0;mt<4;++mt) {
        size_t off = (size_t)(base_ot + mt)*6144 + lane*8;
        pAh[mt] = Wgh + off;
        pAl[mt] = Wgl + off;
    }
    #pragma unroll
    for (int nt=0;nt<8;++nt) {
        int cb = (w&1)*128 + nt*16;
        int t = cb >> 6;
        int ntile = (n0 >> 4) + ((cb & 63) >> 4);
        pB[nt] = s2 + ((size_t)(t*B_ + b)*16 + ntile)*6144 + lane*8;
    }

    f32x4 acc[4][8];
    #pragma unroll
    for (int mt=0;mt<4;++mt)
        #pragma unroll
        for (int nt=0;nt<8;++nt) { acc[mt][nt][0]=0.f; acc[mt][nt][1]=0.f; acc[mt][nt][2]=0.f; acc[mt][nt][3]=0.f; }

    #pragma unroll
    for (int ks = 0; ks < 12; ++ks) {
        bf16x8 ah[4], al[4], bb[8];
        #pragma unroll
        for (int mt=0;mt<4;++mt) {
            ah[mt] = *(const bf16x8*)(pAh[mt]); pAh[mt] += 512;
            al[mt] = *(const bf16x8*)(pAl[mt]); pAl[mt] += 512;
        }
        #pragma unroll
        for (int nt=0;nt<8;++nt) { bb[nt] = *(const bf16x8*)(pB[nt]); pB[nt] += 512; }
        #pragma unroll
        for (int mt=0;mt<4;++mt)
            #pragma unroll
            for (int nt=0;nt<8;++nt) {
                acc[mt][nt] = __builtin_amdgcn_mfma_f32_16x16x32_bf16(ah[mt], bb[nt], acc[mt][nt], 0,0,0);
                acc[mt][nt] = __builtin_amdgcn_mfma_f32_16x16x32_bf16(al[mt], bb[nt], acc[mt][nt], 0,0,0);
            }
    }

    for (int r = 0; r < 4; ++r) {
        __syncthreads();
        int erow = (w>>1)*16 + quad*4;
        #pragma unroll
        for (int nt=0;nt<8;++nt) {
            int col = (w&1)*128 + nt*16 + lc;
            Ep[(erow+0)*260 + col] = acc[r][nt][0];
            Ep[(erow+1)*260 + col] = acc[r][nt][1];
            Ep[(erow+2)*260 + col] = acc[r][nt][2];
            Ep[(erow+3)*260 + col] = acc[r][nt][3];
        }
        __syncthreads();
        #pragma unroll
        for (int q=0;q<8;++q) {
            int e = q*256 + tid;
            int orow = e >> 6;
            int rem = e & 63;
            int t = rem >> 4, nq = rem & 15;
            int oloc = ((orow & 16) ? 64 : 0) + r*16 + (orow & 15);
            int o = o0 + oloc;
            float4 f = *(const float4*)&Ep[orow*260 + t*64 + nq*4];
            float inv = BNi[oloc], off = BNo[oloc];
            float4 rr = make_float4(f.x*inv+off, f.y*inv+off, f.z*inv+off, f.w*inv+off);
            *(float4*)(out + (((size_t)t*B_ + b)*C_ + o)*N_ + n0 + nq*4) = rr;
        }
    }
}

extern "C" void kernel_launch(void* const* d_in, const int* in_sizes, int n_in,
                              void* d_out, int out_size, void* d_ws, size_t ws_size,
                              hipStream_t stream) {
    const float* x  = (const float*)d_in[0];
    char* ws = (char*)d_ws;
    unsigned short* S0 = (unsigned short*)ws;
    unsigned short* Q  = (unsigned short*)(ws + 25165824);
    unsigned short* K  = (unsigned short*)(ws + 50331648);
    unsigned short* V  = (unsigned short*)(ws + 75497472);
    unsigned short* WHI = (unsigned short*)(ws + 100663296);
    unsigned short* WLO = WHI + 4*147456;
    unsigned short* S2 = (unsigned short*)ws;     // reuses S0 region
    float* AO = (float*)d_out;                    // d_out (50 MB) as attn scratch; k_proj overwrites last

    k_wsplit<<<dim3(72,4), 256, 0, stream>>>(
        (const float*)d_in[2], (const float*)d_in[7], (const float*)d_in[12],
        (const float*)d_in[17], WHI, WLO);

    k_lif1<<<dim3(32,6,4), 256, 0, stream>>>(x, S0);

    Br2 ba;
    for (int z=0;z<3;++z) { ba.whi[z] = WHI + z*147456; ba.wlo[z] = WLO + z*147456; }
    ba.g[0]=(const float*)d_in[3];  ba.be[0]=(const float*)d_in[4];
    ba.me[0]=(const float*)d_in[5]; ba.va[0]=(const float*)d_in[6];
    ba.g[1]=(const float*)d_in[8];  ba.be[1]=(const float*)d_in[9];
    ba.me[1]=(const float*)d_in[10]; ba.va[1]=(const float*)d_in[11];
    ba.g[2]=(const float*)d_in[13]; ba.be[2]=(const float*)d_in[14];
    ba.me[2]=(const float*)d_in[15]; ba.va[2]=(const float*)d_in[16];
    ba.out[0]=Q; ba.out[1]=K; ba.out[2]=V;
    k_branch<<<dim3(128, 3, 3), 256, 0, stream>>>(S0, ba);

    k_attn<<<T_*B_*NH_, 256, 0, stream>>>(Q, K, V, AO);
    k_lif3<<<dim3(B_*NH_, 6), 256, 0, stream>>>(AO, S2);

    k_proj<<<dim3(128, 3), 256, 0, stream>>>(S2,
        WHI + 3*147456, WLO + 3*147456,
        (const float*)d_in[18],
        (const float*)d_in[19], (const float*)d_in[20],
        (const float*)d_in[21], (const float*)d_in[22],
        (float*)d_out);
}

// Round 8
// 277.872 us; speedup vs baseline: 1.1199x; 1.1199x over previous
//
#include <hip/hip_runtime.h>
#include <hip/hip_bf16.h>

// SpikingSelfAttention: T=4 B=32 C=384 N=256 NH=8 D=48
#define T_  4
#define B_  32
#define C_  384
#define N_  256
#define NH_ 8
#define D_  48

typedef __attribute__((ext_vector_type(8))) short bf16x8;
typedef __attribute__((ext_vector_type(4))) float f32x4;

__device__ __forceinline__ float bf2f(unsigned short s) {
    return __uint_as_float(((unsigned int)s) << 16);
}
__device__ __forceinline__ unsigned short f2bf(float f) {
    __hip_bfloat16 h = __float2bfloat16(f);
    return __builtin_bit_cast(unsigned short, h);
}

// ---- K0: split fp32 weights into hi/lo bf16, FRAGMENT-MAJOR [otile24][ks12][lane64][8] ----
__global__ __launch_bounds__(256) void k_wsplit(const float* __restrict__ w0,
                                                const float* __restrict__ w1,
                                                const float* __restrict__ w2,
                                                const float* __restrict__ w3,
                                                unsigned short* __restrict__ hi,
                                                unsigned short* __restrict__ lo) {
    const float* w = (blockIdx.y==0) ? w0 : (blockIdx.y==1) ? w1 : (blockIdx.y==2) ? w2 : w3;
    int g = blockIdx.x*256 + threadIdx.x;            // 0..18431 (72 blocks)
    int otile = g / 768;
    int rem = g - otile*768;
    int lane = rem & 63;
    int o  = otile*16 + (lane & 15);
    int k0 = (rem >> 6)*32 + (lane >> 4)*8;
    const float* src = w + (size_t)o*C_ + k0;
    unsigned short h8[8], l8[8];
    #pragma unroll
    for (int j=0;j<8;++j) {
        float f = src[j];
        h8[j] = f2bf(f);
        l8[j] = f2bf(f - bf2f(h8[j]));
    }
    size_t dst = (size_t)blockIdx.y*147456 + (size_t)g*8;
    *(uint4*)(hi + dst) = *(uint4*)h8;
    *(uint4*)(lo + dst) = *(uint4*)l8;
}

// ---- K1: LIF over T on x; spikes bf16 FRAGMENT-MAJOR: [t][b][ntile16][ks12][lane64][8] ----
__global__ __launch_bounds__(256) void k_lif1(const float* __restrict__ x,
                                              unsigned short* __restrict__ s0) {
    __shared__ unsigned short Tt[64*72];
    const int tid = threadIdx.x;
    const int b  = blockIdx.x;
    const int c0 = blockIdx.y * 64;
    const int n0 = blockIdx.z * 64;
    const int ci = tid >> 2;
    const int nj = (tid & 3) * 16;
    float v[16];
    #pragma unroll
    for (int i=0;i<16;++i) v[i]=0.f;
    for (int t = 0; t < T_; ++t) {
        const float* xp = x + (((size_t)t*B_ + b)*C_ + c0 + ci)*N_ + n0 + nj;
        #pragma unroll
        for (int q=0;q<4;++q) {
            float4 f = *(const float4*)(xp + q*4);
            float e[4] = {f.x,f.y,f.z,f.w};
            #pragma unroll
            for (int j=0;j<4;++j) {
                int ii = q*4+j;
                float h = v[ii] + (e[j] - v[ii])*0.5f;
                bool sp = (h - 1.0f) >= 0.f;
                v[ii] = sp ? 0.f : h;
                Tt[(nj + ii)*72 + ci] = sp ? 0x3F80u : 0u;
            }
        }
        __syncthreads();
        int nrow = tid >> 2, cch = (tid & 3)*16;
        int n = n0 + nrow;
        uint4 u0 = *(const uint4*)&Tt[nrow*72 + cch];
        uint4 u1 = *(const uint4*)&Tt[nrow*72 + cch + 8];
        size_t tb16 = ((size_t)(t*B_ + b)*16 + (n>>4))*12;
        int c8a = c0 + cch, c8b = c0 + cch + 8;
        *(uint4*)(s0 + (tb16 + (c8a>>5))*512 + (((c8a>>3)&3)*16 + (n&15))*8) = u0;
        *(uint4*)(s0 + (tb16 + (c8b>>5))*512 + (((c8b>>3)&3)*16 + (n&15))*8) = u1;
        __syncthreads();
    }
}

// ---- K2: MFMA branch GEMM, 128x256 tiles; Q/K/V spikes out as BITMASKS [t][b][o][32B] ----
struct Br2 {
    const unsigned short* whi[3];
    const unsigned short* wlo[3];
    const float *g[3], *be[3], *me[3], *va[3];
    unsigned char* outb[3];
};

__global__ __launch_bounds__(256, 2) void k_branch(const unsigned short* __restrict__ s0, Br2 a) {
    __shared__ float Ep[32*260];
    __shared__ float BNi[128], BNo[128];
    const int tid = threadIdx.x;
    const int z  = blockIdx.z;
    const int o0 = blockIdx.y * 128;
    const int bx = blockIdx.x;               // col-tile fastest for L2 affinity
    const int b  = bx >> 2;
    const int n0 = (bx & 3) * 64;
    const int w    = tid >> 6;
    const int lane = tid & 63;
    const int quad = lane >> 4;
    const int lc   = lane & 15;
    const unsigned short* __restrict__ Wgh = a.whi[z];
    const unsigned short* __restrict__ Wgl = a.wlo[z];

    if (tid < 128) {
        int o = o0 + tid;
        float inv = a.g[z][o] / sqrtf(a.va[z][o] + 1e-5f);
        BNi[tid] = inv;
        BNo[tid] = a.be[z][o] - a.me[z][o]*inv;
    }

    const int base_ot = (o0 >> 4) + (w >> 1)*4;
    const unsigned short* pAh[4];
    const unsigned short* pAl[4];
    const unsigned short* pB[8];
    #pragma unroll
    for (int mt=0;mt<4;++mt) {
        size_t off = (size_t)(base_ot + mt)*6144 + lane*8;
        pAh[mt] = Wgh + off;
        pAl[mt] = Wgl + off;
    }
    #pragma unroll
    for (int nt=0;nt<8;++nt) {
        int cb = (w&1)*128 + nt*16;
        int t = cb >> 6;
        int ntile = (n0 >> 4) + ((cb & 63) >> 4);
        pB[nt] = s0 + ((size_t)(t*B_ + b)*16 + ntile)*6144 + lane*8;
    }

    f32x4 acc[4][8];
    #pragma unroll
    for (int mt=0;mt<4;++mt)
        #pragma unroll
        for (int nt=0;nt<8;++nt) { acc[mt][nt][0]=0.f; acc[mt][nt][1]=0.f; acc[mt][nt][2]=0.f; acc[mt][nt][3]=0.f; }

    #pragma unroll
    for (int ks = 0; ks < 12; ++ks) {
        bf16x8 ah[4], al[4], bb[8];
        #pragma unroll
        for (int mt=0;mt<4;++mt) {
            ah[mt] = *(const bf16x8*)(pAh[mt]); pAh[mt] += 512;
            al[mt] = *(const bf16x8*)(pAl[mt]); pAl[mt] += 512;
        }
        #pragma unroll
        for (int nt=0;nt<8;++nt) { bb[nt] = *(const bf16x8*)(pB[nt]); pB[nt] += 512; }
        #pragma unroll
        for (int mt=0;mt<4;++mt)
            #pragma unroll
            for (int nt=0;nt<8;++nt) {
                acc[mt][nt] = __builtin_amdgcn_mfma_f32_16x16x32_bf16(ah[mt], bb[nt], acc[mt][nt], 0,0,0);
                acc[mt][nt] = __builtin_amdgcn_mfma_f32_16x16x32_bf16(al[mt], bb[nt], acc[mt][nt], 0,0,0);
            }
    }

    // epilogue: 4 rounds; Ep = 32 o x 256 col (col = t*64 + nn); 1-byte bitmask stores
    unsigned char* outb = a.outb[z];
    for (int r = 0; r < 4; ++r) {
        __syncthreads();
        int erow = (w>>1)*16 + quad*4;
        #pragma unroll
        for (int nt=0;nt<8;++nt) {
            int col = (w&1)*128 + nt*16 + lc;
            Ep[(erow+0)*260 + col] = acc[r][nt][0];
            Ep[(erow+1)*260 + col] = acc[r][nt][1];
            Ep[(erow+2)*260 + col] = acc[r][nt][2];
            Ep[(erow+3)*260 + col] = acc[r][nt][3];
        }
        __syncthreads();
        {
            int orow = tid >> 3;                 // 0..31
            int ns8 = (tid & 7) * 8;
            int oloc = ((orow & 16) ? 64 : 0) + r*16 + (orow & 15);
            int o = o0 + oloc;
            float inv = BNi[oloc], off = BNo[oloc];
            float v[8];
            #pragma unroll
            for (int j=0;j<8;++j) v[j]=0.f;
            #pragma unroll
            for (int t=0;t<4;++t) {
                float4 f0 = *(const float4*)&Ep[orow*260 + t*64 + ns8];
                float4 f1 = *(const float4*)&Ep[orow*260 + t*64 + ns8 + 4];
                float e[8] = {f0.x,f0.y,f0.z,f0.w,f1.x,f1.y,f1.z,f1.w};
                unsigned byte = 0;
                #pragma unroll
                for (int j=0;j<8;++j) {
                    float y = e[j]*inv + off;
                    float h = v[j] + (y - v[j])*0.5f;
                    bool sp = (h - 1.0f) >= 0.f;
                    v[j] = sp ? 0.f : h;
                    byte |= (sp ? 1u : 0u) << j;
                }
                outb[((size_t)(t*B_ + b)*C_ + o)*32 + (n0 >> 3) + (tid & 7)] = (unsigned char)byte;
            }
        }
    }
}

// ---- K3: fused attention + attn-LIF per (b,h), bit inputs; S2 bf16 fragment-major out ----
// per t: KtV[dd1][dd2] = popcount(Krow & Vrow) (exact ints <=256, bf16-exact);
//        AO = Qt @ KtVb (MFMA, K=64 padded); LIF in regs; spikes -> LDS -> coalesced S2
__global__ __launch_bounds__(256) void k_attn(const unsigned char* __restrict__ qb,
                                              const unsigned char* __restrict__ kb,
                                              const unsigned char* __restrict__ vb,
                                              unsigned short* __restrict__ s2) {
    __shared__ unsigned short Qt[256*72];        // [n][dd] bf16; pads 48..63 zero; reused as Sp
    __shared__ unsigned short KtVb[48*72];       // [dd2][dd1] bf16; pads 48..63 zero
    __shared__ unsigned long long KB[192], VB[192], QB[192];   // 48 rows x 4 u64
    const int tid = threadIdx.x;
    const int w = tid >> 6, lane = tid & 63, quad = lane >> 4, lc = lane & 15;
    const int bh = blockIdx.x;
    const int b  = bh >> 3, hh = bh & 7;

    // zero pads once (never rewritten)
    *(uint4*)&Qt[tid*72 + 48] = make_uint4(0,0,0,0);
    *(uint4*)&Qt[tid*72 + 56] = make_uint4(0,0,0,0);
    if (tid < 48) {
        *(uint4*)&KtVb[tid*72 + 48] = make_uint4(0,0,0,0);
        *(uint4*)&KtVb[tid*72 + 56] = make_uint4(0,0,0,0);
    }

    float vst[4][3][4];
    #pragma unroll
    for (int j=0;j<4;++j)
        #pragma unroll
        for (int nt=0;nt<3;++nt)
            #pragma unroll
            for (int r=0;r<4;++r) vst[j][nt][r]=0.f;

    for (int t = 0; t < T_; ++t) {
        __syncthreads();                          // prev iter readers done
        const size_t bitbase = ((size_t)(t*B_ + b)*C_ + hh*D_)*32;
        if (tid < 192) {
            KB[tid] = *(const unsigned long long*)(kb + bitbase + tid*8);
            VB[tid] = *(const unsigned long long*)(vb + bitbase + tid*8);
            QB[tid] = *(const unsigned long long*)(qb + bitbase + tid*8);
        }
        __syncthreads();
        // Qt expand: thread = n; QB word broadcast per wave
        {
            int q64 = tid >> 6, sh = tid & 63;
            #pragma unroll
            for (int dd=0; dd<48; ++dd)
                Qt[tid*72 + dd] = ((QB[dd*4 + q64] >> sh) & 1ULL) ? 0x3F80u : 0u;
        }
        // KtV popcount: 2304 pairs
        #pragma unroll
        for (int i=0;i<9;++i) {
            int p = tid + i*256;
            if (p < 2304) {
                int dd1 = p / 48, dd2 = p - dd1*48;
                const unsigned long long* kr = &KB[dd1*4];
                const unsigned long long* vr = &VB[dd2*4];
                int c = __popcll(kr[0]&vr[0]) + __popcll(kr[1]&vr[1])
                      + __popcll(kr[2]&vr[2]) + __popcll(kr[3]&vr[3]);
                KtVb[dd2*72 + dd1] = f2bf((float)c);
            }
        }
        __syncthreads();
        // phase2 MFMA: M=256 (4 mt/wave), N=48 (3 tiles), K=64 (2 steps)
        f32x4 acc2[4][3];
        #pragma unroll
        for (int j=0;j<4;++j)
            #pragma unroll
            for (int nt=0;nt<3;++nt) { acc2[j][nt][0]=0.f; acc2[j][nt][1]=0.f; acc2[j][nt][2]=0.f; acc2[j][nt][3]=0.f; }
        #pragma unroll
        for (int k2=0; k2<2; ++k2) {
            bf16x8 bfr[3];
            #pragma unroll
            for (int nt=0;nt<3;++nt)
                bfr[nt] = *(const bf16x8*)&KtVb[(nt*16 + lc)*72 + k2*32 + quad*8];
            #pragma unroll
            for (int j=0;j<4;++j) {
                bf16x8 af = *(const bf16x8*)&Qt[((w*4 + j)*16 + lc)*72 + k2*32 + quad*8];
                #pragma unroll
                for (int nt=0;nt<3;++nt)
                    acc2[j][nt] = __builtin_amdgcn_mfma_f32_16x16x32_bf16(af, bfr[nt], acc2[j][nt], 0,0,0);
            }
        }
        // LIF + spike write into Sp (= Qt region; rows [w*64,w*64+64) are wave-private)
        #pragma unroll
        for (int j=0;j<4;++j) {
            int nr = (w*4 + j)*16 + quad*4;
            #pragma unroll
            for (int nt=0;nt<3;++nt)
                #pragma unroll
                for (int r=0;r<4;++r) {
                    float y = acc2[j][nt][r]*0.125f;
                    float vv = vst[j][nt][r];
                    float h = vv + (y - vv)*0.5f;
                    bool s = (h - 1.0f) >= 0.f;
                    vst[j][nt][r] = s ? 0.f : h;
                    Qt[(nr + r)*72 + nt*16 + lc] = s ? 0x3F80u : 0u;
                }
        }
        __syncthreads();
        // flush: thread n=tid, 6 coalesced 16B chunks -> S2 fragment-major
        {
            size_t tb16 = ((size_t)(t*B_ + b)*16 + (tid>>4))*12;
            #pragma unroll
            for (int c8=0; c8<6; ++c8) {
                int ci = hh*6 + c8;
                size_t dst = (tb16 + (ci>>2))*512 + (size_t)(((ci&3)*16 + (tid&15))*8);
                *(uint4*)(s2 + dst) = *(uint4*)&Qt[tid*72 + c8*8];
            }
        }
    }
}

// ---- K5: proj MFMA GEMM + bias + BN -> out [T][B][C][N] fp32, 128x256 tiles ----
__global__ __launch_bounds__(256, 2) void k_proj(const unsigned short* __restrict__ s2,
        const unsigned short* __restrict__ Wgh, const unsigned short* __restrict__ Wgl,
        const float* __restrict__ pb,
        const float* __restrict__ g, const float* __restrict__ be,
        const float* __restrict__ me, const float* __restrict__ va,
        float* __restrict__ out) {
    __shared__ float Ep[32*260];
    __shared__ float BNi[128], BNo[128];
    const int tid = threadIdx.x;
    const int o0 = blockIdx.y * 128;
    const int bx = blockIdx.x;
    const int b  = bx >> 2;
    const int n0 = (bx & 3) * 64;
    const int w    = tid >> 6;
    const int lane = tid & 63;
    const int quad = lane >> 4;
    const int lc   = lane & 15;

    if (tid < 128) {
        int o = o0 + tid;
        float inv = g[o] / sqrtf(va[o] + 1e-5f);
        BNi[tid] = inv;
        BNo[tid] = be[o] - me[o]*inv + pb[o]*inv;
    }

    const int base_ot = (o0 >> 4) + (w >> 1)*4;
    const unsigned short* pAh[4];
    const unsigned short* pAl[4];
    const unsigned short* pB[8];
    #pragma unroll
    for (int mt=0;mt<4;++mt) {
        size_t off = (size_t)(base_ot + mt)*6144 + lane*8;
        pAh[mt] = Wgh + off;
        pAl[mt] = Wgl + off;
    }
    #pragma unroll
    for (int nt=0;nt<8;++nt) {
        int cb = (w&1)*128 + nt*16;
        int t = cb >> 6;
        int ntile = (n0 >> 4) + ((cb & 63) >> 4);
        pB[nt] = s2 + ((size_t)(t*B_ + b)*16 + ntile)*6144 + lane*8;
    }

    f32x4 acc[4][8];
    #pragma unroll
    for (int mt=0;mt<4;++mt)
        #pragma unroll
        for (int nt=0;nt<8;++nt) { acc[mt][nt][0]=0.f; acc[mt][nt][1]=0.f; acc[mt][nt][2]=0.f; acc[mt][nt][3]=0.f; }

    #pragma unroll
    for (int ks = 0; ks < 12; ++ks) {
        bf16x8 ah[4], al[4], bb[8];
        #pragma unroll
        for (int mt=0;mt<4;++mt) {
            ah[mt] = *(const bf16x8*)(pAh[mt]); pAh[mt] += 512;
            al[mt] = *(const bf16x8*)(pAl[mt]); pAl[mt] += 512;
        }
        #pragma unroll
        for (int nt=0;nt<8;++nt) { bb[nt] = *(const bf16x8*)(pB[nt]); pB[nt] += 512; }
        #pragma unroll
        for (int mt=0;mt<4;++mt)
            #pragma unroll
            for (int nt=0;nt<8;++nt) {
                acc[mt][nt] = __builtin_amdgcn_mfma_f32_16x16x32_bf16(ah[mt], bb[nt], acc[mt][nt], 0,0,0);
                acc[mt][nt] = __builtin_amdgcn_mfma_f32_16x16x32_bf16(al[mt], bb[nt], acc[mt][nt], 0,0,0);
            }
    }

    for (int r = 0; r < 4; ++r) {
        __syncthreads();
        int erow = (w>>1)*16 + quad*4;
        #pragma unroll
        for (int nt=0;nt<8;++nt) {
            int col = (w&1)*128 + nt*16 + lc;
            Ep[(erow+0)*260 + col] = acc[r][nt][0];
            Ep[(erow+1)*260 + col] = acc[r][nt][1];
            Ep[(erow+2)*260 + col] = acc[r][nt][2];
            Ep[(erow+3)*260 + col] = acc[r][nt][3];
        }
        __syncthreads();
        #pragma unroll
        for (int q=0;q<8;++q) {
            int e = q*256 + tid;
            int orow = e >> 6;
            int rem = e & 63;
            int t = rem >> 4, nq = rem & 15;
            int oloc = ((orow & 16) ? 64 : 0) + r*16 + (orow & 15);
            int o = o0 + oloc;
            float4 f = *(const float4*)&Ep[orow*260 + t*64 + nq*4];
            float inv = BNi[oloc], off = BNo[oloc];
            float4 rr = make_float4(f.x*inv+off, f.y*inv+off, f.z*inv+off, f.w*inv+off);
            *(float4*)(out + (((size_t)t*B_ + b)*C_ + o)*N_ + n0 + nq*4) = rr;
        }
    }
}

extern "C" void kernel_launch(void* const* d_in, const int* in_sizes, int n_in,
                              void* d_out, int out_size, void* d_ws, size_t ws_size,
                              hipStream_t stream) {
    const float* x  = (const float*)d_in[0];
    char* ws = (char*)d_ws;
    unsigned short* S0 = (unsigned short*)ws;
    unsigned char* QB = (unsigned char*)(ws + 25165824);
    unsigned char* KB = (unsigned char*)(ws + 25165824 + 2097152);
    unsigned char* VB = (unsigned char*)(ws + 25165824 + 4194304);
    unsigned short* WHI = (unsigned short*)(ws + 100663296);
    unsigned short* WLO = WHI + 4*147456;
    unsigned short* S2 = (unsigned short*)ws;     // reuses S0 region (S0 consumed by k_branch)

    k_wsplit<<<dim3(72,4), 256, 0, stream>>>(
        (const float*)d_in[2], (const float*)d_in[7], (const float*)d_in[12],
        (const float*)d_in[17], WHI, WLO);

    k_lif1<<<dim3(32,6,4), 256, 0, stream>>>(x, S0);

    Br2 ba;
    for (int z=0;z<3;++z) { ba.whi[z] = WHI + z*147456; ba.wlo[z] = WLO + z*147456; }
    ba.g[0]=(const float*)d_in[3];  ba.be[0]=(const float*)d_in[4];
    ba.me[0]=(const float*)d_in[5]; ba.va[0]=(const float*)d_in[6];
    ba.g[1]=(const float*)d_in[8];  ba.be[1]=(const float*)d_in[9];
    ba.me[1]=(const float*)d_in[10]; ba.va[1]=(const float*)d_in[11];
    ba.g[2]=(const float*)d_in[13]; ba.be[2]=(const float*)d_in[14];
    ba.me[2]=(const float*)d_in[15]; ba.va[2]=(const float*)d_in[16];
    ba.outb[0]=QB; ba.outb[1]=KB; ba.outb[2]=VB;
    k_branch<<<dim3(128, 3, 3), 256, 0, stream>>>(S0, ba);

    k_attn<<<B_*NH_, 256, 0, stream>>>(QB, KB, VB, S2);

    k_proj<<<dim3(128, 3), 256, 0, stream>>>(S2,
        WHI + 3*147456, WLO + 3*147456,
        (const float*)d_in[18],
        (const float*)d_in[19], (const float*)d_in[20],
        (const float*)d_in[21], (const float*)d_in[22],
        (float*)d_out);
}

// Round 9
// 226.194 us; speedup vs baseline: 1.3758x; 1.2285x over previous
//
#include <hip/hip_runtime.h>
#include <hip/hip_bf16.h>

// SpikingSelfAttention: T=4 B=32 C=384 N=256 NH=8 D=48
#define T_  4
#define B_  32
#define C_  384
#define N_  256
#define NH_ 8
#define D_  48

typedef __attribute__((ext_vector_type(8))) short bf16x8;
typedef __attribute__((ext_vector_type(4))) float f32x4;

__device__ __forceinline__ float bf2f(unsigned short s) {
    return __uint_as_float(((unsigned int)s) << 16);
}
__device__ __forceinline__ unsigned short f2bf(float f) {
    __hip_bfloat16 h = __float2bfloat16(f);
    return __builtin_bit_cast(unsigned short, h);
}

// ---- K0: split fp32 weights into hi/lo bf16, FRAGMENT-MAJOR [otile24][ks12][lane64][8] ----
__global__ __launch_bounds__(256) void k_wsplit(const float* __restrict__ w0,
                                                const float* __restrict__ w1,
                                                const float* __restrict__ w2,
                                                const float* __restrict__ w3,
                                                unsigned short* __restrict__ hi,
                                                unsigned short* __restrict__ lo) {
    const float* w = (blockIdx.y==0) ? w0 : (blockIdx.y==1) ? w1 : (blockIdx.y==2) ? w2 : w3;
    int g = blockIdx.x*256 + threadIdx.x;            // 0..18431 (72 blocks)
    int otile = g / 768;
    int rem = g - otile*768;
    int lane = rem & 63;
    int o  = otile*16 + (lane & 15);
    int k0 = (rem >> 6)*32 + (lane >> 4)*8;
    const float* src = w + (size_t)o*C_ + k0;
    unsigned short h8[8], l8[8];
    #pragma unroll
    for (int j=0;j<8;++j) {
        float f = src[j];
        h8[j] = f2bf(f);
        l8[j] = f2bf(f - bf2f(h8[j]));
    }
    size_t dst = (size_t)blockIdx.y*147456 + (size_t)g*8;
    *(uint4*)(hi + dst) = *(uint4*)h8;
    *(uint4*)(lo + dst) = *(uint4*)l8;
}

// ---- K1: LIF over T on x; spike BITS fragment-major bytes [t][b][nt16][ks12][lane64] ----
__global__ __launch_bounds__(256) void k_lif1(const float* __restrict__ x,
                                              unsigned char* __restrict__ s0b) {
    __shared__ unsigned short Tt[64*72];
    const int tid = threadIdx.x;
    const int b  = blockIdx.x;
    const int c0 = blockIdx.y * 64;
    const int n0 = blockIdx.z * 64;
    const int ci = tid >> 2;
    const int nj = (tid & 3) * 16;
    float v[16];
    #pragma unroll
    for (int i=0;i<16;++i) v[i]=0.f;
    for (int t = 0; t < T_; ++t) {
        const float* xp = x + (((size_t)t*B_ + b)*C_ + c0 + ci)*N_ + n0 + nj;
        #pragma unroll
        for (int q=0;q<4;++q) {
            float4 f = *(const float4*)(xp + q*4);
            float e[4] = {f.x,f.y,f.z,f.w};
            #pragma unroll
            for (int j=0;j<4;++j) {
                int ii = q*4+j;
                float h = v[ii] + (e[j] - v[ii])*0.5f;
                bool sp = (h - 1.0f) >= 0.f;
                v[ii] = sp ? 0.f : h;
                Tt[(nj + ii)*72 + ci] = sp ? 0x3F80u : 0u;
            }
        }
        __syncthreads();
        #pragma unroll
        for (int half=0; half<2; ++half) {
            int e = tid + half*256;              // 0..511
            int nl = e >> 3, cbyte = e & 7;      // n-local, c-byte (8 c each)
            unsigned short tmp[8];
            *(uint4*)tmp = *(const uint4*)&Tt[nl*72 + cbyte*8];
            unsigned byte = 0;
            #pragma unroll
            for (int j=0;j<8;++j) byte |= (tmp[j] ? 1u : 0u) << j;
            int n = n0 + nl, c = c0 + cbyte*8;
            int ks = c >> 5, kc = (c >> 3) & 3;
            size_t dst = ((((size_t)(t*B_ + b)*16 + (n>>4))*12 + ks)*64) + kc*16 + (n & 15);
            s0b[dst] = (unsigned char)byte;
        }
        __syncthreads();
    }
}

// ---- K2: MFMA branch GEMM, 128x256 tiles; B from bit-bytes via LDS LUT; Q/K/V bits out ----
struct Br2 {
    const unsigned short* whi[3];
    const unsigned short* wlo[3];
    const float *g[3], *be[3], *me[3], *va[3];
    unsigned char* outb[3];
};

__global__ __launch_bounds__(256, 2) void k_branch(const unsigned char* __restrict__ s0b, Br2 a) {
    __shared__ float Ep[32*260];
    __shared__ float BNi[128], BNo[128];
    __shared__ unsigned short LUT[2048];         // [byte][8] bf16 expansion
    const int tid = threadIdx.x;
    const int z  = blockIdx.z;
    const int o0 = blockIdx.y * 128;
    const int bx = blockIdx.x;
    const int b  = bx >> 2;
    const int n0 = (bx & 3) * 64;
    const int nt0 = bx & 3;
    const int w    = tid >> 6;
    const int lane = tid & 63;
    const int quad = lane >> 4;
    const int lc   = lane & 15;
    const unsigned short* __restrict__ Wgh = a.whi[z];
    const unsigned short* __restrict__ Wgl = a.wlo[z];

    #pragma unroll
    for (int j=0;j<8;++j) LUT[tid*8 + j] = ((tid >> j) & 1) ? 0x3F80u : 0u;
    if (tid < 128) {
        int o = o0 + tid;
        float inv = a.g[z][o] / sqrtf(a.va[z][o] + 1e-5f);
        BNi[tid] = inv;
        BNo[tid] = a.be[z][o] - a.me[z][o]*inv;
    }
    __syncthreads();

    const int base_ot = (o0 >> 4) + (w >> 1)*4;
    const unsigned short* pAh[4];
    const unsigned short* pAl[4];
    const unsigned char* pBY[8];
    #pragma unroll
    for (int mt=0;mt<4;++mt) {
        size_t off = (size_t)(base_ot + mt)*6144 + lane*8;
        pAh[mt] = Wgh + off;
        pAl[mt] = Wgl + off;
    }
    #pragma unroll
    for (int nt=0;nt<8;++nt) {
        int cb = (w&1)*128 + nt*16;
        int t = cb >> 6;
        int ntile = (n0 >> 4) + ((cb & 63) >> 4);
        pBY[nt] = s0b + ((size_t)(t*B_ + b)*16 + ntile)*768 + lane;
    }

    f32x4 acc[4][8];
    #pragma unroll
    for (int mt=0;mt<4;++mt)
        #pragma unroll
        for (int nt=0;nt<8;++nt) { acc[mt][nt][0]=0.f; acc[mt][nt][1]=0.f; acc[mt][nt][2]=0.f; acc[mt][nt][3]=0.f; }

    #pragma unroll
    for (int ks = 0; ks < 12; ++ks) {
        bf16x8 ah[4], al[4], bb[8];
        unsigned char byt[8];
        #pragma unroll
        for (int nt=0;nt<8;++nt) { byt[nt] = *(pBY[nt]); pBY[nt] += 64; }
        #pragma unroll
        for (int mt=0;mt<4;++mt) {
            ah[mt] = *(const bf16x8*)(pAh[mt]); pAh[mt] += 512;
            al[mt] = *(const bf16x8*)(pAl[mt]); pAl[mt] += 512;
        }
        #pragma unroll
        for (int nt=0;nt<8;++nt) bb[nt] = *(const bf16x8*)&LUT[(int)byt[nt]*8];
        #pragma unroll
        for (int mt=0;mt<4;++mt)
            #pragma unroll
            for (int nt=0;nt<8;++nt) {
                acc[mt][nt] = __builtin_amdgcn_mfma_f32_16x16x32_bf16(ah[mt], bb[nt], acc[mt][nt], 0,0,0);
                acc[mt][nt] = __builtin_amdgcn_mfma_f32_16x16x32_bf16(al[mt], bb[nt], acc[mt][nt], 0,0,0);
            }
    }

    // epilogue: 4 rounds; bits out [t][b][nt4][o][8B] (block owns whole lines)
    unsigned char* outb = a.outb[z];
    for (int r = 0; r < 4; ++r) {
        __syncthreads();
        int erow = (w>>1)*16 + quad*4;
        #pragma unroll
        for (int nt=0;nt<8;++nt) {
            int col = (w&1)*128 + nt*16 + lc;
            Ep[(erow+0)*260 + col] = acc[r][nt][0];
            Ep[(erow+1)*260 + col] = acc[r][nt][1];
            Ep[(erow+2)*260 + col] = acc[r][nt][2];
            Ep[(erow+3)*260 + col] = acc[r][nt][3];
        }
        __syncthreads();
        {
            int orow = tid >> 3;                 // 0..31
            int ns8 = (tid & 7) * 8;
            int oloc = ((orow & 16) ? 64 : 0) + r*16 + (orow & 15);
            int o = o0 + oloc;
            float inv = BNi[oloc], off = BNo[oloc];
            float v[8];
            #pragma unroll
            for (int j=0;j<8;++j) v[j]=0.f;
            #pragma unroll
            for (int t=0;t<4;++t) {
                float4 f0 = *(const float4*)&Ep[orow*260 + t*64 + ns8];
                float4 f1 = *(const float4*)&Ep[orow*260 + t*64 + ns8 + 4];
                float e[8] = {f0.x,f0.y,f0.z,f0.w,f1.x,f1.y,f1.z,f1.w};
                unsigned byte = 0;
                #pragma unroll
                for (int j=0;j<8;++j) {
                    float y = e[j]*inv + off;
                    float h = v[j] + (y - v[j])*0.5f;
                    bool sp = (h - 1.0f) >= 0.f;
                    v[j] = sp ? 0.f : h;
                    byte |= (sp ? 1u : 0u) << j;
                }
                outb[(((size_t)(t*B_ + b)*4 + nt0)*C_ + o)*8 + (tid & 7)] = (unsigned char)byte;
            }
        }
    }
}

// ---- K3: fused attention + attn-LIF per (b,h), bit in/out; S2 bits fragment-major bytes ----
__global__ __launch_bounds__(256) void k_attn(const unsigned char* __restrict__ qb,
                                              const unsigned char* __restrict__ kb,
                                              const unsigned char* __restrict__ vb,
                                              unsigned char* __restrict__ s2b) {
    __shared__ unsigned short Qt[256*72];        // [n][dd] bf16; pads 48..63 zero; reused for spikes
    __shared__ unsigned short KtVb[48*72];       // [dd2][dd1] bf16; pads 48..63 zero
    __shared__ unsigned long long KB[192], VB[192], QB[192];   // 48 rows x 4 u64 (n-bits)
    const int tid = threadIdx.x;
    const int w = tid >> 6, lane = tid & 63, quad = lane >> 4, lc = lane & 15;
    const int bh = blockIdx.x;
    const int b  = bh >> 3, hh = bh & 7;

    *(uint4*)&Qt[tid*72 + 48] = make_uint4(0,0,0,0);
    *(uint4*)&Qt[tid*72 + 56] = make_uint4(0,0,0,0);
    if (tid < 48) {
        *(uint4*)&KtVb[tid*72 + 48] = make_uint4(0,0,0,0);
        *(uint4*)&KtVb[tid*72 + 56] = make_uint4(0,0,0,0);
    }

    float vst[4][3][4];
    #pragma unroll
    for (int j=0;j<4;++j)
        #pragma unroll
        for (int nt=0;nt<3;++nt)
            #pragma unroll
            for (int r=0;r<4;++r) vst[j][nt][r]=0.f;

    for (int t = 0; t < T_; ++t) {
        __syncthreads();
        if (tid < 192) {
            int dd = tid >> 2, j = tid & 3;      // u64 j covers n in [j*64, j*64+64)
            size_t src = (((size_t)(t*B_ + b)*4 + j)*C_ + hh*D_ + dd)*8;
            KB[tid] = *(const unsigned long long*)(kb + src);
            VB[tid] = *(const unsigned long long*)(vb + src);
            QB[tid] = *(const unsigned long long*)(qb + src);
        }
        __syncthreads();
        {
            int q64 = tid >> 6, sh = tid & 63;   // NOTE: KB/QB indexed [dd*4 + word]
            #pragma unroll
            for (int dd=0; dd<48; ++dd)
                Qt[tid*72 + dd] = ((QB[dd*4 + q64] >> sh) & 1ULL) ? 0x3F80u : 0u;
        }
        #pragma unroll
        for (int i=0;i<9;++i) {
            int p = tid + i*256;
            if (p < 2304) {
                int dd1 = p / 48, dd2 = p - dd1*48;
                const unsigned long long* kr = &KB[dd1*4];
                const unsigned long long* vr = &VB[dd2*4];
                int c = __popcll(kr[0]&vr[0]) + __popcll(kr[1]&vr[1])
                      + __popcll(kr[2]&vr[2]) + __popcll(kr[3]&vr[3]);
                KtVb[dd2*72 + dd1] = f2bf((float)c);
            }
        }
        __syncthreads();
        f32x4 acc2[4][3];
        #pragma unroll
        for (int j=0;j<4;++j)
            #pragma unroll
            for (int nt=0;nt<3;++nt) { acc2[j][nt][0]=0.f; acc2[j][nt][1]=0.f; acc2[j][nt][2]=0.f; acc2[j][nt][3]=0.f; }
        #pragma unroll
        for (int k2=0; k2<2; ++k2) {
            bf16x8 bfr[3];
            #pragma unroll
            for (int nt=0;nt<3;++nt)
                bfr[nt] = *(const bf16x8*)&KtVb[(nt*16 + lc)*72 + k2*32 + quad*8];
            #pragma unroll
            for (int j=0;j<4;++j) {
                bf16x8 af = *(const bf16x8*)&Qt[((w*4 + j)*16 + lc)*72 + k2*32 + quad*8];
                #pragma unroll
                for (int nt=0;nt<3;++nt)
                    acc2[j][nt] = __builtin_amdgcn_mfma_f32_16x16x32_bf16(af, bfr[nt], acc2[j][nt], 0,0,0);
            }
        }
        // LIF + spike write into Qt (rows [w*64,w*64+64) wave-private)
        #pragma unroll
        for (int j=0;j<4;++j) {
            int nr = (w*4 + j)*16 + quad*4;
            #pragma unroll
            for (int nt=0;nt<3;++nt)
                #pragma unroll
                for (int r=0;r<4;++r) {
                    float y = acc2[j][nt][r]*0.125f;
                    float vv = vst[j][nt][r];
                    float h = vv + (y - vv)*0.5f;
                    bool s = (h - 1.0f) >= 0.f;
                    vst[j][nt][r] = s ? 0.f : h;
                    Qt[(nr + r)*72 + nt*16 + lc] = s ? 0x3F80u : 0u;
                }
        }
        __syncthreads();
        // flush: pack 8-dd bytes -> S2 bits fragment-major [t][b][nt16][ks12][lane64]
        {
            #pragma unroll
            for (int c8=0; c8<6; ++c8) {
                unsigned short tmp[8];
                *(uint4*)tmp = *(const uint4*)&Qt[tid*72 + c8*8];
                unsigned byte = 0;
                #pragma unroll
                for (int j=0;j<8;++j) byte |= (tmp[j] ? 1u : 0u) << j;
                int ci = hh*6 + c8;              // global c-byte = (hh*48 + c8*8)/8
                int ks = ci >> 2, kc = ci & 3;
                size_t dst = ((((size_t)(t*B_ + b)*16 + (tid>>4))*12 + ks)*64) + kc*16 + (tid & 15);
                s2b[dst] = (unsigned char)byte;
            }
        }
    }
}

// ---- K5: proj MFMA GEMM + bias + BN -> out [T][B][C][N] fp32; B from bit-bytes via LUT ----
__global__ __launch_bounds__(256, 2) void k_proj(const unsigned char* __restrict__ s2b,
        const unsigned short* __restrict__ Wgh, const unsigned short* __restrict__ Wgl,
        const float* __restrict__ pb,
        const float* __restrict__ g, const float* __restrict__ be,
        const float* __restrict__ me, const float* __restrict__ va,
        float* __restrict__ out) {
    __shared__ float Ep[32*260];
    __shared__ float BNi[128], BNo[128];
    __shared__ unsigned short LUT[2048];
    const int tid = threadIdx.x;
    const int o0 = blockIdx.y * 128;
    const int bx = blockIdx.x;
    const int b  = bx >> 2;
    const int n0 = (bx & 3) * 64;
    const int w    = tid >> 6;
    const int lane = tid & 63;
    const int quad = lane >> 4;
    const int lc   = lane & 15;

    #pragma unroll
    for (int j=0;j<8;++j) LUT[tid*8 + j] = ((tid >> j) & 1) ? 0x3F80u : 0u;
    if (tid < 128) {
        int o = o0 + tid;
        float inv = g[o] / sqrtf(va[o] + 1e-5f);
        BNi[tid] = inv;
        BNo[tid] = be[o] - me[o]*inv + pb[o]*inv;
    }
    __syncthreads();

    const int base_ot = (o0 >> 4) + (w >> 1)*4;
    const unsigned short* pAh[4];
    const unsigned short* pAl[4];
    const unsigned char* pBY[8];
    #pragma unroll
    for (int mt=0;mt<4;++mt) {
        size_t off = (size_t)(base_ot + mt)*6144 + lane*8;
        pAh[mt] = Wgh + off;
        pAl[mt] = Wgl + off;
    }
    #pragma unroll
    for (int nt=0;nt<8;++nt) {
        int cb = (w&1)*128 + nt*16;
        int t = cb >> 6;
        int ntile = (n0 >> 4) + ((cb & 63) >> 4);
        pBY[nt] = s2b + ((size_t)(t*B_ + b)*16 + ntile)*768 + lane;
    }

    f32x4 acc[4][8];
    #pragma unroll
    for (int mt=0;mt<4;++mt)
        #pragma unroll
        for (int nt=0;nt<8;++nt) { acc[mt][nt][0]=0.f; acc[mt][nt][1]=0.f; acc[mt][nt][2]=0.f; acc[mt][nt][3]=0.f; }

    #pragma unroll
    for (int ks = 0; ks < 12; ++ks) {
        bf16x8 ah[4], al[4], bb[8];
        unsigned char byt[8];
        #pragma unroll
        for (int nt=0;nt<8;++nt) { byt[nt] = *(pBY[nt]); pBY[nt] += 64; }
        #pragma unroll
        for (int mt=0;mt<4;++mt) {
            ah[mt] = *(const bf16x8*)(pAh[mt]); pAh[mt] += 512;
            al[mt] = *(const bf16x8*)(pAl[mt]); pAl[mt] += 512;
        }
        #pragma unroll
        for (int nt=0;nt<8;++nt) bb[nt] = *(const bf16x8*)&LUT[(int)byt[nt]*8];
        #pragma unroll
        for (int mt=0;mt<4;++mt)
            #pragma unroll
            for (int nt=0;nt<8;++nt) {
                acc[mt][nt] = __builtin_amdgcn_mfma_f32_16x16x32_bf16(ah[mt], bb[nt], acc[mt][nt], 0,0,0);
                acc[mt][nt] = __builtin_amdgcn_mfma_f32_16x16x32_bf16(al[mt], bb[nt], acc[mt][nt], 0,0,0);
            }
    }

    for (int r = 0; r < 4; ++r) {
        __syncthreads();
        int erow = (w>>1)*16 + quad*4;
        #pragma unroll
        for (int nt=0;nt<8;++nt) {
            int col = (w&1)*128 + nt*16 + lc;
            Ep[(erow+0)*260 + col] = acc[r][nt][0];
            Ep[(erow+1)*260 + col] = acc[r][nt][1];
            Ep[(erow+2)*260 + col] = acc[r][nt][2];
            Ep[(erow+3)*260 + col] = acc[r][nt][3];
        }
        __syncthreads();
        #pragma unroll
        for (int q=0;q<8;++q) {
            int e = q*256 + tid;
            int orow = e >> 6;
            int rem = e & 63;
            int t = rem >> 4, nq = rem & 15;
            int oloc = ((orow & 16) ? 64 : 0) + r*16 + (orow & 15);
            int o = o0 + oloc;
            float4 f = *(const float4*)&Ep[orow*260 + t*64 + nq*4];
            float inv = BNi[oloc], off = BNo[oloc];
            float4 rr = make_float4(f.x*inv+off, f.y*inv+off, f.z*inv+off, f.w*inv+off);
            *(float4*)(out + (((size_t)t*B_ + b)*C_ + o)*N_ + n0 + nq*4) = rr;
        }
    }
}

extern "C" void kernel_launch(void* const* d_in, const int* in_sizes, int n_in,
                              void* d_out, int out_size, void* d_ws, size_t ws_size,
                              hipStream_t stream) {
    const float* x  = (const float*)d_in[0];
    char* ws = (char*)d_ws;
    unsigned char* S0B = (unsigned char*)ws;                 // 1.57 MB
    unsigned char* QB = (unsigned char*)(ws + 2097152);
    unsigned char* KB = (unsigned char*)(ws + 4194304);
    unsigned char* VB = (unsigned char*)(ws + 6291456);
    unsigned char* S2B = (unsigned char*)(ws + 8388608);
    unsigned short* WHI = (unsigned short*)(ws + 100663296);
    unsigned short* WLO = WHI + 4*147456;

    k_wsplit<<<dim3(72,4), 256, 0, stream>>>(
        (const float*)d_in[2], (const float*)d_in[7], (const float*)d_in[12],
        (const float*)d_in[17], WHI, WLO);

    k_lif1<<<dim3(32,6,4), 256, 0, stream>>>(x, S0B);

    Br2 ba;
    for (int z=0;z<3;++z) { ba.whi[z] = WHI + z*147456; ba.wlo[z] = WLO + z*147456; }
    ba.g[0]=(const float*)d_in[3];  ba.be[0]=(const float*)d_in[4];
    ba.me[0]=(const float*)d_in[5]; ba.va[0]=(const float*)d_in[6];
    ba.g[1]=(const float*)d_in[8];  ba.be[1]=(const float*)d_in[9];
    ba.me[1]=(const float*)d_in[10]; ba.va[1]=(const float*)d_in[11];
    ba.g[2]=(const float*)d_in[13]; ba.be[2]=(const float*)d_in[14];
    ba.me[2]=(const float*)d_in[15]; ba.va[2]=(const float*)d_in[16];
    ba.outb[0]=QB; ba.outb[1]=KB; ba.outb[2]=VB;
    k_branch<<<dim3(128, 3, 3), 256, 0, stream>>>(S0B, ba);

    k_attn<<<B_*NH_, 256, 0, stream>>>(QB, KB, VB, S2B);

    k_proj<<<dim3(128, 3), 256, 0, stream>>>(S2B,
        WHI + 3*147456, WLO + 3*147456,
        (const float*)d_in[18],
        (const float*)d_in[19], (const float*)d_in[20],
        (const float*)d_in[21], (const float*)d_in[22],
        (float*)d_out);
}

// Round 10
// 217.836 us; speedup vs baseline: 1.4286x; 1.0384x over previous
//
#include <hip/hip_runtime.h>
#include <hip/hip_bf16.h>

// SpikingSelfAttention: T=4 B=32 C=384 N=256 NH=8 D=48
#define T_  4
#define B_  32
#define C_  384
#define N_  256
#define NH_ 8
#define D_  48

typedef __attribute__((ext_vector_type(8))) short bf16x8;
typedef __attribute__((ext_vector_type(4))) float f32x4;

__device__ __forceinline__ float bf2f(unsigned short s) {
    return __uint_as_float(((unsigned int)s) << 16);
}
__device__ __forceinline__ unsigned short f2bf(float f) {
    __hip_bfloat16 h = __float2bfloat16(f);
    return __builtin_bit_cast(unsigned short, h);
}

// ---- K0: split fp32 weights into hi/lo bf16, FRAGMENT-MAJOR [otile24][ks12][lane64][8] ----
__global__ __launch_bounds__(256) void k_wsplit(const float* __restrict__ w0,
                                                const float* __restrict__ w1,
                                                const float* __restrict__ w2,
                                                const float* __restrict__ w3,
                                                unsigned short* __restrict__ hi,
                                                unsigned short* __restrict__ lo) {
    const float* w = (blockIdx.y==0) ? w0 : (blockIdx.y==1) ? w1 : (blockIdx.y==2) ? w2 : w3;
    int g = blockIdx.x*256 + threadIdx.x;            // 0..18431 (72 blocks)
    int otile = g / 768;
    int rem = g - otile*768;
    int lane = rem & 63;
    int o  = otile*16 + (lane & 15);
    int k0 = (rem >> 6)*32 + (lane >> 4)*8;
    const float* src = w + (size_t)o*C_ + k0;
    unsigned short h8[8], l8[8];
    #pragma unroll
    for (int j=0;j<8;++j) {
        float f = src[j];
        h8[j] = f2bf(f);
        l8[j] = f2bf(f - bf2f(h8[j]));
    }
    size_t dst = (size_t)blockIdx.y*147456 + (size_t)g*8;
    *(uint4*)(hi + dst) = *(uint4*)h8;
    *(uint4*)(lo + dst) = *(uint4*)l8;
}

// ---- K1: LIF over T on x; spike BITS fragment-major bytes [t][b][nt16][ks12][lane64] ----
__global__ __launch_bounds__(256) void k_lif1(const float* __restrict__ x,
                                              unsigned char* __restrict__ s0b) {
    __shared__ unsigned short Tt[64*72];
    const int tid = threadIdx.x;
    const int b  = blockIdx.x;
    const int c0 = blockIdx.y * 64;
    const int n0 = blockIdx.z * 64;
    const int ci = tid >> 2;
    const int nj = (tid & 3) * 16;
    float v[16];
    #pragma unroll
    for (int i=0;i<16;++i) v[i]=0.f;
    for (int t = 0; t < T_; ++t) {
        const float* xp = x + (((size_t)t*B_ + b)*C_ + c0 + ci)*N_ + n0 + nj;
        #pragma unroll
        for (int q=0;q<4;++q) {
            float4 f = *(const float4*)(xp + q*4);
            float e[4] = {f.x,f.y,f.z,f.w};
            #pragma unroll
            for (int j=0;j<4;++j) {
                int ii = q*4+j;
                float h = v[ii] + (e[j] - v[ii])*0.5f;
                bool sp = (h - 1.0f) >= 0.f;
                v[ii] = sp ? 0.f : h;
                Tt[(nj + ii)*72 + ci] = sp ? 0x3F80u : 0u;
            }
        }
        __syncthreads();
        #pragma unroll
        for (int half=0; half<2; ++half) {
            int e = tid + half*256;              // 0..511
            int nl = e >> 3, cbyte = e & 7;      // n-local, c-byte (8 c each)
            unsigned short tmp[8];
            *(uint4*)tmp = *(const uint4*)&Tt[nl*72 + cbyte*8];
            unsigned byte = 0;
            #pragma unroll
            for (int j=0;j<8;++j) byte |= (tmp[j] ? 1u : 0u) << j;
            int n = n0 + nl, c = c0 + cbyte*8;
            int ks = c >> 5, kc = (c >> 3) & 3;
            size_t dst = ((((size_t)(t*B_ + b)*16 + (n>>4))*12 + ks)*64) + kc*16 + (n & 15);
            s0b[dst] = (unsigned char)byte;
        }
        __syncthreads();
    }
}

// ---- K2: MFMA branch GEMM, 128x128 tiles (4t x 32n cols); bits out [t][b][g32][o][4B] ----
struct Br2 {
    const unsigned short* whi[3];
    const unsigned short* wlo[3];
    const float *g[3], *be[3], *me[3], *va[3];
    unsigned char* outb[3];
};

__global__ __launch_bounds__(256, 2) void k_branch(const unsigned char* __restrict__ s0b, Br2 a) {
    __shared__ float Ep[32*132];
    __shared__ float BNi[128], BNo[128];
    __shared__ unsigned short LUT[2048];
    const int tid = threadIdx.x;
    const int z  = blockIdx.z;
    const int o0 = blockIdx.y * 128;
    const int bx = blockIdx.x;               // col-tile fastest for L2 affinity
    const int b  = bx >> 3;
    const int n0 = (bx & 7) * 32;
    const int g32 = n0 >> 5;
    const int w    = tid >> 6;
    const int lane = tid & 63;
    const int quad = lane >> 4;
    const int lc   = lane & 15;
    const unsigned short* __restrict__ Wgh = a.whi[z];
    const unsigned short* __restrict__ Wgl = a.wlo[z];

    #pragma unroll
    for (int j=0;j<8;++j) LUT[tid*8 + j] = ((tid >> j) & 1) ? 0x3F80u : 0u;
    if (tid < 128) {
        int o = o0 + tid;
        float inv = a.g[z][o] / sqrtf(a.va[z][o] + 1e-5f);
        BNi[tid] = inv;
        BNo[tid] = a.be[z][o] - a.me[z][o]*inv;
    }
    __syncthreads();

    const int base_ot = (o0 >> 4) + (w >> 1)*4;
    const unsigned short* pAh[4];
    const unsigned short* pAl[4];
    const unsigned char* pBY[4];
    #pragma unroll
    for (int mt=0;mt<4;++mt) {
        size_t off = (size_t)(base_ot + mt)*6144 + lane*8;
        pAh[mt] = Wgh + off;
        pAl[mt] = Wgl + off;
    }
    #pragma unroll
    for (int nt=0;nt<4;++nt) {
        int cb = (w&1)*64 + nt*16;           // col = t*32 + ns
        int t = cb >> 5;
        int ntile = (n0 >> 4) + ((cb >> 4) & 1);
        pBY[nt] = s0b + ((size_t)(t*B_ + b)*16 + ntile)*768 + lane;
    }

    f32x4 acc[4][4];
    #pragma unroll
    for (int mt=0;mt<4;++mt)
        #pragma unroll
        for (int nt=0;nt<4;++nt) { acc[mt][nt][0]=0.f; acc[mt][nt][1]=0.f; acc[mt][nt][2]=0.f; acc[mt][nt][3]=0.f; }

    #pragma unroll
    for (int ks = 0; ks < 12; ++ks) {
        bf16x8 ah[4], al[4], bb[4];
        unsigned char byt[4];
        #pragma unroll
        for (int nt=0;nt<4;++nt) { byt[nt] = *(pBY[nt]); pBY[nt] += 64; }
        #pragma unroll
        for (int mt=0;mt<4;++mt) {
            ah[mt] = *(const bf16x8*)(pAh[mt]); pAh[mt] += 512;
            al[mt] = *(const bf16x8*)(pAl[mt]); pAl[mt] += 512;
        }
        #pragma unroll
        for (int nt=0;nt<4;++nt) bb[nt] = *(const bf16x8*)&LUT[(int)byt[nt]*8];
        #pragma unroll
        for (int mt=0;mt<4;++mt)
            #pragma unroll
            for (int nt=0;nt<4;++nt) {
                acc[mt][nt] = __builtin_amdgcn_mfma_f32_16x16x32_bf16(ah[mt], bb[nt], acc[mt][nt], 0,0,0);
                acc[mt][nt] = __builtin_amdgcn_mfma_f32_16x16x32_bf16(al[mt], bb[nt], acc[mt][nt], 0,0,0);
            }
    }

    // epilogue: 4 rounds; Ep = 32 o x 128 col (col = t*32 + ns); 1-byte (8n) stores, block owns lines
    unsigned char* outb = a.outb[z];
    for (int r = 0; r < 4; ++r) {
        __syncthreads();
        int erow = (w>>1)*16 + quad*4;
        #pragma unroll
        for (int nt=0;nt<4;++nt) {
            int col = (w&1)*64 + nt*16 + lc;
            Ep[(erow+0)*132 + col] = acc[r][nt][0];
            Ep[(erow+1)*132 + col] = acc[r][nt][1];
            Ep[(erow+2)*132 + col] = acc[r][nt][2];
            Ep[(erow+3)*132 + col] = acc[r][nt][3];
        }
        __syncthreads();
        if (tid < 128) {
            int orow = tid >> 2;                 // 0..31
            int bidx = tid & 3;                  // byte within 32-n group
            int oloc = ((orow & 16) ? 64 : 0) + r*16 + (orow & 15);
            int o = o0 + oloc;
            float inv = BNi[oloc], off = BNo[oloc];
            float v[8];
            #pragma unroll
            for (int j=0;j<8;++j) v[j]=0.f;
            #pragma unroll
            for (int t=0;t<4;++t) {
                float4 f0 = *(const float4*)&Ep[orow*132 + t*32 + bidx*8];
                float4 f1 = *(const float4*)&Ep[orow*132 + t*32 + bidx*8 + 4];
                float e[8] = {f0.x,f0.y,f0.z,f0.w,f1.x,f1.y,f1.z,f1.w};
                unsigned byte = 0;
                #pragma unroll
                for (int j=0;j<8;++j) {
                    float y = e[j]*inv + off;
                    float h = v[j] + (y - v[j])*0.5f;
                    bool sp = (h - 1.0f) >= 0.f;
                    v[j] = sp ? 0.f : h;
                    byte |= (sp ? 1u : 0u) << j;
                }
                outb[(((size_t)(t*B_ + b)*8 + g32)*C_ + o)*4 + bidx] = (unsigned char)byte;
            }
        }
    }
}

// ---- K3: fused attention + attn-LIF per (b,h); bits in [t][b][g32][o][4B]; S2 frag-major bytes ----
__global__ __launch_bounds__(256) void k_attn(const unsigned char* __restrict__ qb,
                                              const unsigned char* __restrict__ kb,
                                              const unsigned char* __restrict__ vb,
                                              unsigned char* __restrict__ s2b) {
    __shared__ unsigned short Qt[256*72];        // [n][dd] bf16; pads 48..63 zero; reused for spikes
    __shared__ unsigned short KtVb[48*72];       // [dd2][dd1] bf16; pads 48..63 zero
    __shared__ unsigned long long KB[192], VB[192], QB[192];   // [dd][word4] n-bit words
    const int tid = threadIdx.x;
    const int w = tid >> 6, lane = tid & 63, quad = lane >> 4, lc = lane & 15;
    const int bh = blockIdx.x;
    const int b  = bh >> 3, hh = bh & 7;

    *(uint4*)&Qt[tid*72 + 48] = make_uint4(0,0,0,0);
    *(uint4*)&Qt[tid*72 + 56] = make_uint4(0,0,0,0);
    if (tid < 48) {
        *(uint4*)&KtVb[tid*72 + 48] = make_uint4(0,0,0,0);
        *(uint4*)&KtVb[tid*72 + 56] = make_uint4(0,0,0,0);
    }

    float vst[4][3][4];
    #pragma unroll
    for (int j=0;j<4;++j)
        #pragma unroll
        for (int nt=0;nt<3;++nt)
            #pragma unroll
            for (int r=0;r<4;++r) vst[j][nt][r]=0.f;

    for (int t = 0; t < T_; ++t) {
        __syncthreads();
        if (tid < 192) {
            int dd = tid >> 2, w64 = tid & 3;    // word covers n in [w64*64, w64*64+64)
            size_t s0 = (((size_t)(t*B_ + b)*8 + 2*w64)*C_ + hh*D_ + dd)*4;
            size_t s1 = s0 + (size_t)C_*4;
            KB[tid] = (unsigned long long)*(const unsigned int*)(kb + s0)
                    | ((unsigned long long)*(const unsigned int*)(kb + s1) << 32);
            VB[tid] = (unsigned long long)*(const unsigned int*)(vb + s0)
                    | ((unsigned long long)*(const unsigned int*)(vb + s1) << 32);
            QB[tid] = (unsigned long long)*(const unsigned int*)(qb + s0)
                    | ((unsigned long long)*(const unsigned int*)(qb + s1) << 32);
        }
        __syncthreads();
        {
            int q64 = tid >> 6, sh = tid & 63;
            #pragma unroll
            for (int dd=0; dd<48; ++dd)
                Qt[tid*72 + dd] = ((QB[dd*4 + q64] >> sh) & 1ULL) ? 0x3F80u : 0u;
        }
        #pragma unroll
        for (int i=0;i<9;++i) {
            int p = tid + i*256;
            if (p < 2304) {
                int dd1 = p / 48, dd2 = p - dd1*48;
                const unsigned long long* kr = &KB[dd1*4];
                const unsigned long long* vr = &VB[dd2*4];
                int c = __popcll(kr[0]&vr[0]) + __popcll(kr[1]&vr[1])
                      + __popcll(kr[2]&vr[2]) + __popcll(kr[3]&vr[3]);
                KtVb[dd2*72 + dd1] = f2bf((float)c);
            }
        }
        __syncthreads();
        f32x4 acc2[4][3];
        #pragma unroll
        for (int j=0;j<4;++j)
            #pragma unroll
            for (int nt=0;nt<3;++nt) { acc2[j][nt][0]=0.f; acc2[j][nt][1]=0.f; acc2[j][nt][2]=0.f; acc2[j][nt][3]=0.f; }
        #pragma unroll
        for (int k2=0; k2<2; ++k2) {
            bf16x8 bfr[3];
            #pragma unroll
            for (int nt=0;nt<3;++nt)
                bfr[nt] = *(const bf16x8*)&KtVb[(nt*16 + lc)*72 + k2*32 + quad*8];
            #pragma unroll
            for (int j=0;j<4;++j) {
                bf16x8 af = *(const bf16x8*)&Qt[((w*4 + j)*16 + lc)*72 + k2*32 + quad*8];
                #pragma unroll
                for (int nt=0;nt<3;++nt)
                    acc2[j][nt] = __builtin_amdgcn_mfma_f32_16x16x32_bf16(af, bfr[nt], acc2[j][nt], 0,0,0);
            }
        }
        #pragma unroll
        for (int j=0;j<4;++j) {
            int nr = (w*4 + j)*16 + quad*4;
            #pragma unroll
            for (int nt=0;nt<3;++nt)
                #pragma unroll
                for (int r=0;r<4;++r) {
                    float y = acc2[j][nt][r]*0.125f;
                    float vv = vst[j][nt][r];
                    float h = vv + (y - vv)*0.5f;
                    bool s = (h - 1.0f) >= 0.f;
                    vst[j][nt][r] = s ? 0.f : h;
                    Qt[(nr + r)*72 + nt*16 + lc] = s ? 0x3F80u : 0u;
                }
        }
        __syncthreads();
        {
            #pragma unroll
            for (int c8=0; c8<6; ++c8) {
                unsigned short tmp[8];
                *(uint4*)tmp = *(const uint4*)&Qt[tid*72 + c8*8];
                unsigned byte = 0;
                #pragma unroll
                for (int j=0;j<8;++j) byte |= (tmp[j] ? 1u : 0u) << j;
                int ci = hh*6 + c8;
                int ks = ci >> 2, kc = ci & 3;
                size_t dst = ((((size_t)(t*B_ + b)*16 + (tid>>4))*12 + ks)*64) + kc*16 + (tid & 15);
                s2b[dst] = (unsigned char)byte;
            }
        }
    }
}

// ---- K5: proj MFMA GEMM, 128x128 single-t tiles (768 blocks); B frag-major bytes via LUT ----
__global__ __launch_bounds__(256, 2) void k_proj(const unsigned char* __restrict__ s2b,
        const unsigned short* __restrict__ Wgh, const unsigned short* __restrict__ Wgl,
        const float* __restrict__ pb,
        const float* __restrict__ g, const float* __restrict__ be,
        const float* __restrict__ me, const float* __restrict__ va,
        float* __restrict__ out) {
    __shared__ float Ep[32*132];
    __shared__ float BNi[128], BNo[128];
    __shared__ unsigned short LUT[2048];
    const int tid = threadIdx.x;
    const int o0 = blockIdx.y * 128;
    const int bx = blockIdx.x;                   // 0..255: t(4) x b(32) x nh(2)
    const int t  = bx >> 6;
    const int b  = (bx >> 1) & 31;
    const int n0 = (bx & 1) * 128;
    const int w    = tid >> 6;
    const int lane = tid & 63;
    const int quad = lane >> 4;
    const int lc   = lane & 15;

    #pragma unroll
    for (int j=0;j<8;++j) LUT[tid*8 + j] = ((tid >> j) & 1) ? 0x3F80u : 0u;
    if (tid < 128) {
        int o = o0 + tid;
        float inv = g[o] / sqrtf(va[o] + 1e-5f);
        BNi[tid] = inv;
        BNo[tid] = be[o] - me[o]*inv + pb[o]*inv;
    }
    __syncthreads();

    const int base_ot = (o0 >> 4) + (w >> 1)*4;
    const unsigned short* pAh[4];
    const unsigned short* pAl[4];
    const unsigned char* pBY[4];
    #pragma unroll
    for (int mt=0;mt<4;++mt) {
        size_t off = (size_t)(base_ot + mt)*6144 + lane*8;
        pAh[mt] = Wgh + off;
        pAl[mt] = Wgl + off;
    }
    #pragma unroll
    for (int nt=0;nt<4;++nt) {
        int cb = (w&1)*64 + nt*16;
        int ntile = (n0 >> 4) + (cb >> 4);
        pBY[nt] = s2b + ((size_t)(t*B_ + b)*16 + ntile)*768 + lane;
    }

    f32x4 acc[4][4];
    #pragma unroll
    for (int mt=0;mt<4;++mt)
        #pragma unroll
        for (int nt=0;nt<4;++nt) { acc[mt][nt][0]=0.f; acc[mt][nt][1]=0.f; acc[mt][nt][2]=0.f; acc[mt][nt][3]=0.f; }

    #pragma unroll
    for (int ks = 0; ks < 12; ++ks) {
        bf16x8 ah[4], al[4], bb[4];
        unsigned char byt[4];
        #pragma unroll
        for (int nt=0;nt<4;++nt) { byt[nt] = *(pBY[nt]); pBY[nt] += 64; }
        #pragma unroll
        for (int mt=0;mt<4;++mt) {
            ah[mt] = *(const bf16x8*)(pAh[mt]); pAh[mt] += 512;
            al[mt] = *(const bf16x8*)(pAl[mt]); pAl[mt] += 512;
        }
        #pragma unroll
        for (int nt=0;nt<4;++nt) bb[nt] = *(const bf16x8*)&LUT[(int)byt[nt]*8];
        #pragma unroll
        for (int mt=0;mt<4;++mt)
            #pragma unroll
            for (int nt=0;nt<4;++nt) {
                acc[mt][nt] = __builtin_amdgcn_mfma_f32_16x16x32_bf16(ah[mt], bb[nt], acc[mt][nt], 0,0,0);
                acc[mt][nt] = __builtin_amdgcn_mfma_f32_16x16x32_bf16(al[mt], bb[nt], acc[mt][nt], 0,0,0);
            }
    }

    for (int r = 0; r < 4; ++r) {
        __syncthreads();
        int erow = (w>>1)*16 + quad*4;
        #pragma unroll
        for (int nt=0;nt<4;++nt) {
            int col = (w&1)*64 + nt*16 + lc;
            Ep[(erow+0)*132 + col] = acc[r][nt][0];
            Ep[(erow+1)*132 + col] = acc[r][nt][1];
            Ep[(erow+2)*132 + col] = acc[r][nt][2];
            Ep[(erow+3)*132 + col] = acc[r][nt][3];
        }
        __syncthreads();
        #pragma unroll
        for (int q=0;q<4;++q) {
            int e = q*256 + tid;                 // 0..1023 = 32 o x 32 n-quads
            int orow = e >> 5;
            int nq = e & 31;
            int oloc = ((orow & 16) ? 64 : 0) + r*16 + (orow & 15);
            int o = o0 + oloc;
            float4 f = *(const float4*)&Ep[orow*132 + nq*4];
            float inv = BNi[oloc], off = BNo[oloc];
            float4 rr = make_float4(f.x*inv+off, f.y*inv+off, f.z*inv+off, f.w*inv+off);
            *(float4*)(out + (((size_t)t*B_ + b)*C_ + o)*N_ + n0 + nq*4) = rr;
        }
    }
}

extern "C" void kernel_launch(void* const* d_in, const int* in_sizes, int n_in,
                              void* d_out, int out_size, void* d_ws, size_t ws_size,
                              hipStream_t stream) {
    const float* x  = (const float*)d_in[0];
    char* ws = (char*)d_ws;
    unsigned char* S0B = (unsigned char*)ws;
    unsigned char* QB = (unsigned char*)(ws + 2097152);
    unsigned char* KB = (unsigned char*)(ws + 4194304);
    unsigned char* VB = (unsigned char*)(ws + 6291456);
    unsigned char* S2B = (unsigned char*)(ws + 8388608);
    unsigned short* WHI = (unsigned short*)(ws + 100663296);
    unsigned short* WLO = WHI + 4*147456;

    k_wsplit<<<dim3(72,4), 256, 0, stream>>>(
        (const float*)d_in[2], (const float*)d_in[7], (const float*)d_in[12],
        (const float*)d_in[17], WHI, WLO);

    k_lif1<<<dim3(32,6,4), 256, 0, stream>>>(x, S0B);

    Br2 ba;
    for (int z=0;z<3;++z) { ba.whi[z] = WHI + z*147456; ba.wlo[z] = WLO + z*147456; }
    ba.g[0]=(const float*)d_in[3];  ba.be[0]=(const float*)d_in[4];
    ba.me[0]=(const float*)d_in[5]; ba.va[0]=(const float*)d_in[6];
    ba.g[1]=(const float*)d_in[8];  ba.be[1]=(const float*)d_in[9];
    ba.me[1]=(const float*)d_in[10]; ba.va[1]=(const float*)d_in[11];
    ba.g[2]=(const float*)d_in[13]; ba.be[2]=(const float*)d_in[14];
    ba.me[2]=(const float*)d_in[15]; ba.va[2]=(const float*)d_in[16];
    ba.outb[0]=QB; ba.outb[1]=KB; ba.outb[2]=VB;
    k_branch<<<dim3(256, 3, 3), 256, 0, stream>>>(S0B, ba);

    k_attn<<<B_*NH_, 256, 0, stream>>>(QB, KB, VB, S2B);

    k_proj<<<dim3(256, 3), 256, 0, stream>>>(S2B,
        WHI + 3*147456, WLO + 3*147456,
        (const float*)d_in[18],
        (const float*)d_in[19], (const float*)d_in[20],
        (const float*)d_in[21], (const float*)d_in[22],
        (float*)d_out);
}